// Round 13
// baseline (325.830 us; speedup 1.0000x reference)
//
#include <hip/hip_runtime.h>

#define N_NODES 100000
#define N_EDGES 1600000
#define D 64
#define CAP 32         // slot cap per node; Poisson(16): P(deg>32)~1e-5/node, ovf backstops
#define OVF_CAP 8192   // overflow edge list (backstop)
#define N_TILES 1563   // (N_NODES + 63) / 64
#define NR 8           // region groups (dst>>14 -> 0..6; r==7 blocks idle)
#define SLICE_EDGES 2048
#define N_SLICES 782   // ceil(N_EDGES / SLICE_EDGES)
#define R1_BLOCKS 64   // stage-1 reduce blocks
#define R1_ROWS 25     // ceil(N_TILES / R1_BLOCKS)
#define ASTRIDE 136    // LDS row stride in bf16 elems (128 + 8 pad, 16B-aligned)

typedef int    vint4  __attribute__((ext_vector_type(4)));
typedef short  s16x4  __attribute__((ext_vector_type(4)));
typedef short  s16x8  __attribute__((ext_vector_type(8)));
typedef float  f32x4  __attribute__((ext_vector_type(4)));
typedef __bf16 bf16x8 __attribute__((ext_vector_type(8)));  // MFMA operand type

// f32 -> bf16 (RNE). Inputs are finite; NaN path not needed.
__device__ inline short f2bf(float f) {
    unsigned u = __builtin_bit_cast(unsigned, f);
    u += 0x7fffu + ((u >> 16) & 1u);
    return (short)(u >> 16);
}
__device__ inline s16x4 f2bf4(float4 v) {
    s16x4 r; r.x = f2bf(v.x); r.y = f2bf(v.y); r.z = f2bf(v.z); r.w = f2bf(v.w);
    return r;
}

// ws layout (bytes) — acc eliminated (gather fused into final):
//   cnt    @ 0        : N_NODES int           (0.4 MB)
//   slots  @ 401408   : N_NODES*CAP int       (12.8 MB)
//   ovfc   @ 13201408 : int
//   ovf    @ 13201424 : OVF_CAP int2
//   part   @ 13267200 : N_TILES*64 float      (0.4 MB)
//   part2  @ 13667328 : R1_BLOCKS*64 float    (16 KB)
#define WS_SLOTS_OFF 401408
#define WS_OVFC_OFF  13201408
#define WS_OVF_OFF   13201424
#define WS_PART_OFF  13267200
#define WS_PART2_OFF 13667328
#define WS_NEEDED    (WS_PART2_OFF + R1_BLOCKS * 64 * 4)

// ---------------------------------------------------------------------------
// Region-partitioned CSR fill (R8/R12-proven: 82us, WRITE 72MB). Block
// r=bIdx&7 scans a 2048-edge slice keeping only dst>>14 == r; region's 2MB
// slot array mostly L2-resident. Nontemporal edge reads.
// ---------------------------------------------------------------------------
__global__ __launch_bounds__(256) void fill_kernel(
    const int* __restrict__ edge_src, const int* __restrict__ edge_dst,
    int* __restrict__ cnt, int* __restrict__ slots,
    int* __restrict__ ovf_cnt, int2* __restrict__ ovf) {
    const int r = blockIdx.x & (NR - 1);
    if (r == 7) return;
    const int slice = blockIdx.x >> 3;
    const int base_e = slice * SLICE_EDGES + threadIdx.x * 8;
    if (base_e >= N_EDGES) return;
    const vint4* s4 = (const vint4*)(edge_src + base_e);
    const vint4* d4 = (const vint4*)(edge_dst + base_e);
    vint4 a0 = __builtin_nontemporal_load(s4);
    vint4 a1 = __builtin_nontemporal_load(s4 + 1);
    vint4 b0 = __builtin_nontemporal_load(d4);
    vint4 b1 = __builtin_nontemporal_load(d4 + 1);
    int ss[8] = {a0.x, a0.y, a0.z, a0.w, a1.x, a1.y, a1.z, a1.w};
    int dd[8] = {b0.x, b0.y, b0.z, b0.w, b1.x, b1.y, b1.z, b1.w};
#pragma unroll
    for (int i = 0; i < 8; ++i) {
        if ((dd[i] >> 14) == r) {
            int pos = atomicAdd(&cnt[dd[i]], 1);
            if (pos < CAP) {
                slots[dd[i] * CAP + pos] = ss[i];
            } else {
                int j = atomicAdd(ovf_cnt, 1);
                if (j < OVF_CAP) ovf[j] = make_int2(ss[i], dd[i]);
            }
        }
    }
}

// ---------------------------------------------------------------------------
// FUSED gather + MFMA final (R13). The separate gather_kernel materialized
// acc (25.6MB write + 25.6MB read-back) only for final to consume once.
// Here each block gathers its 64 nodes' neighbor sums straight into the
// bf16 A-tile in LDS, then runs the R12 MFMA epilogue. Gather: wave w
// handles nodes w*16+t sequentially with the R5 pattern (q=lane>>4 picks
// slot e+q, c4=lane&15 picks float4 column; loads independent across iters
// -> MLP preserved). Overflow edges (normally zero) folded in pre-convert.
// 1563 blocks x 4 waves, ~35KB LDS -> 4 blocks/CU.
// ---------------------------------------------------------------------------
__global__ __launch_bounds__(256) void fused_final_kernel(
    const float* __restrict__ feat, const float* __restrict__ emb,
    const int* __restrict__ cnt, const int* __restrict__ slots,
    const float* __restrict__ W1, const float* __restrict__ b1,
    const float* __restrict__ W2, const float* __restrict__ b2,
    const int* __restrict__ ovf_cnt, const int2* __restrict__ ovf,
    float* __restrict__ partials) {
    __shared__ short A_s[64 * ASTRIDE];  // [node][feat(0..63)|nbr(64..127)] bf16
    __shared__ short W_s[64 * ASTRIDE];  // [o][W1(0..63)|W2(64..127)] bf16
    __shared__ float red[4][64];

    const int tid  = threadIdx.x;
    const int lane = tid & 63;
    const int wave = tid >> 6;
    const int quad = lane >> 4;
    const int col  = lane & 15;
    const int node0 = blockIdx.x * 64;
    const float4* emb4 = (const float4*)emb;

    // Per-lane bias for output o = nb*16 + col.
    float bias[4];
#pragma unroll
    for (int nb = 0; nb < 4; ++nb) bias[nb] = b1[nb * 16 + col] + b2[nb * 16 + col];

    // Stage W (bf16): 1024 float4 per matrix, 4 per thread, coalesced.
    {
        const float4* W1v = (const float4*)W1;
        const float4* W2v = (const float4*)W2;
#pragma unroll
        for (int i = 0; i < 4; ++i) {
            const int flat = tid + i * 256;
            const int row = flat >> 4, c4 = flat & 15;
            *(s16x4*)&W_s[row * ASTRIDE + c4 * 4]      = f2bf4(W1v[flat]);
            *(s16x4*)&W_s[row * ASTRIDE + 64 + c4 * 4] = f2bf4(W2v[flat]);
        }
    }

    // Stage feat rows (bf16) into A_s cols 0..63.
    {
        const float4* fv = (const float4*)feat;
#pragma unroll
        for (int i = 0; i < 4; ++i) {
            const int flat = tid + i * 256;
            const int row = flat >> 4, c4 = flat & 15;
            const int node = node0 + row;
            float4 f = make_float4(0.f, 0.f, 0.f, 0.f);
            if (node < N_NODES) f = fv[(size_t)node * 16 + c4];
            *(s16x4*)&A_s[row * ASTRIDE + c4 * 4] = f2bf4(f);
        }
    }

    // Fused gather: wave handles its 16 nodes; nbr sums -> A_s cols 64..127.
    const int n_ovf_raw = *ovf_cnt;
    const int n_ovf = (n_ovf_raw > OVF_CAP) ? OVF_CAP : n_ovf_raw;
    for (int t = 0; t < 16; ++t) {
        const int v = node0 + wave * 16 + t;
        const int vc = (v < N_NODES) ? v : 0;       // clamp OOB row index
        int deg = (v < N_NODES) ? cnt[v] : 0;
        if (deg > CAP) deg = CAP;
        const int si = slots[(size_t)vc * CAP + (lane & (CAP - 1))];
        float4 sum = make_float4(0.f, 0.f, 0.f, 0.f);
        for (int e = 0; e < deg; e += 4) {
            const int idx = e + quad;
            const int s = __shfl(si, idx & (CAP - 1));
            if (idx < deg) {
                float4 a = emb4[(size_t)s * 16 + col];
                sum.x += a.x; sum.y += a.y; sum.z += a.z; sum.w += a.w;
            }
        }
#pragma unroll
        for (int off = 16; off < 64; off <<= 1) {
            sum.x += __shfl_xor(sum.x, off);
            sum.y += __shfl_xor(sum.y, off);
            sum.z += __shfl_xor(sum.z, off);
            sum.w += __shfl_xor(sum.w, off);
        }
        if (quad == 0) {
            // Overflow contributions (n_ovf ~ 0 in practice).
            for (int i = 0; i < n_ovf; ++i) {
                int2 eo = ovf[i];
                if (eo.y == v) {
                    float4 a = emb4[(size_t)eo.x * 16 + col];
                    sum.x += a.x; sum.y += a.y; sum.z += a.z; sum.w += a.w;
                }
            }
            *(s16x4*)&A_s[(wave * 16 + t) * ASTRIDE + 64 + col * 4] =
                f2bf4(make_float4(sum.x, sum.y, sum.z, sum.w));
        }
    }
    __syncthreads();

    // B-fragments (4 output-blocks x 4 k-steps) hoisted into VGPRs.
    bf16x8 Bf[4][4];
#pragma unroll
    for (int nb = 0; nb < 4; ++nb)
#pragma unroll
        for (int ks = 0; ks < 4; ++ks)
            Bf[nb][ks] = __builtin_bit_cast(bf16x8,
                *(const s16x8*)&W_s[(nb * 16 + col) * ASTRIDE + ks * 32 + quad * 8]);

    f32x4 C[4];
#pragma unroll
    for (int nb = 0; nb < 4; ++nb) C[nb] = (f32x4){0.f, 0.f, 0.f, 0.f};
#pragma unroll
    for (int ks = 0; ks < 4; ++ks) {
        const bf16x8 Af = __builtin_bit_cast(bf16x8,
            *(const s16x8*)&A_s[(wave * 16 + col) * ASTRIDE + ks * 32 + quad * 8]);
#pragma unroll
        for (int nb = 0; nb < 4; ++nb)
            C[nb] = __builtin_amdgcn_mfma_f32_16x16x32_bf16(Af, Bf[nb][ks],
                                                            C[nb], 0, 0, 0);
    }

    // Epilogue: bias + ReLU (C-layout: col=lane&15, row=quad*4+reg), mask OOB
    // nodes, column sums via shfl over quads, cross-wave combine in LDS.
    float sums[4] = {0.f, 0.f, 0.f, 0.f};
#pragma unroll
    for (int nb = 0; nb < 4; ++nb) {
#pragma unroll
        for (int reg = 0; reg < 4; ++reg) {
            const int node = node0 + wave * 16 + quad * 4 + reg;
            float u = C[nb][reg] + bias[nb];
            u = (u > 0.f) ? u : 0.f;
            if (node < N_NODES) sums[nb] += u;
        }
        sums[nb] += __shfl_xor(sums[nb], 16);
        sums[nb] += __shfl_xor(sums[nb], 32);
        if (lane < 16) red[wave][nb * 16 + lane] = sums[nb];
    }
    __syncthreads();
    if (tid < 64) {
        partials[blockIdx.x * 64 + tid] =
            red[0][tid] + red[1][tid] + red[2][tid] + red[3][tid];
    }
}

// ---------------------------------------------------------------------------
// Two-stage partials reduction (R9-proven; single-block version was 110us).
// ---------------------------------------------------------------------------
__global__ __launch_bounds__(256) void reduce1_kernel(
    const float* __restrict__ partials, float* __restrict__ part2) {
    __shared__ float red[4][64];
    const int col = threadIdx.x & 63;
    const int seg = threadIdx.x >> 6;
    const int r0 = blockIdx.x * R1_ROWS;
    int r1 = r0 + R1_ROWS;
    if (r1 > N_TILES) r1 = N_TILES;
    float s = 0.f;
    for (int r = r0 + seg; r < r1; r += 4) s += partials[r * 64 + col];
    red[seg][col] = s;
    __syncthreads();
    if (seg == 0) {
        part2[blockIdx.x * 64 + col] =
            red[0][col] + red[1][col] + red[2][col] + red[3][col];
    }
}

__global__ __launch_bounds__(256) void reduce2_kernel(
    const float* __restrict__ part2, float* __restrict__ out) {
    __shared__ float red[4][64];
    const int col = threadIdx.x & 63;
    const int seg = threadIdx.x >> 6;
    float s = 0.f;
    for (int r = seg; r < R1_BLOCKS; r += 4) s += part2[r * 64 + col];
    red[seg][col] = s;
    __syncthreads();
    if (seg == 0) {
        out[col] = red[0][col] + red[1][col] + red[2][col] + red[3][col];
    }
}

extern "C" void kernel_launch(void* const* d_in, const int* in_sizes, int n_in,
                              void* d_out, int out_size, void* d_ws, size_t ws_size,
                              hipStream_t stream) {
    const float* feat = (const float*)d_in[0];
    const float* emb  = (const float*)d_in[1];
    const float* W1   = (const float*)d_in[2];
    const float* b1   = (const float*)d_in[3];
    const float* W2   = (const float*)d_in[4];
    const float* b2   = (const float*)d_in[5];
    const int* edge_src = (const int*)d_in[6];
    const int* edge_dst = (const int*)d_in[7];
    float* out = (float*)d_out;
    char* ws = (char*)d_ws;

    int*   cnt      = (int*)ws;
    int*   slots    = (int*)(ws + WS_SLOTS_OFF);
    int*   ovf_cnt  = (int*)(ws + WS_OVFC_OFF);
    int2*  ovf      = (int2*)(ws + WS_OVF_OFF);
    float* partials = (float*)(ws + WS_PART_OFF);
    float* part2    = (float*)(ws + WS_PART2_OFF);

    (void)hipMemsetAsync(cnt, 0, N_NODES * sizeof(int), stream);
    (void)hipMemsetAsync(ovf_cnt, 0, sizeof(int), stream);

    fill_kernel<<<NR * N_SLICES, 256, 0, stream>>>(edge_src, edge_dst,
                                                   cnt, slots, ovf_cnt, ovf);
    fused_final_kernel<<<N_TILES, 256, 0, stream>>>(feat, emb, cnt, slots,
                                                    W1, b1, W2, b2,
                                                    ovf_cnt, ovf, partials);
    reduce1_kernel<<<R1_BLOCKS, 256, 0, stream>>>(partials, part2);
    reduce2_kernel<<<1, 256, 0, stream>>>(part2, out);
}

// Round 14
// 270.178 us; speedup vs baseline: 1.2060x; 1.2060x over previous
//
#include <hip/hip_runtime.h>

#define N_NODES 100000
#define N_EDGES 1600000
#define D 64
#define CAP 32         // slot cap per node; Poisson(16): P(deg>32)~1e-5/node, ovf backstops
#define OVF_CAP 8192   // overflow edge list (backstop)
#define N_TILES 1563   // (N_NODES + 63) / 64
#define NR 8           // region groups (dst>>14 -> 0..6; r==7 blocks idle)
#define SLICE_EDGES 2048
#define N_SLICES 782   // ceil(N_EDGES / SLICE_EDGES)
#define R1_BLOCKS 64   // stage-1 reduce blocks
#define R1_ROWS 25     // ceil(N_TILES / R1_BLOCKS)
#define ASTRIDE 136    // LDS row stride in bf16 elems (128 + 8 pad, 16B-aligned)

typedef int    vint4  __attribute__((ext_vector_type(4)));
typedef short  s16x4  __attribute__((ext_vector_type(4)));
typedef short  s16x8  __attribute__((ext_vector_type(8)));
typedef float  f32x4  __attribute__((ext_vector_type(4)));
typedef __bf16 bf16x8 __attribute__((ext_vector_type(8)));  // MFMA operand type

// f32 -> bf16 (RNE). Inputs are finite; NaN path not needed.
__device__ inline short f2bf(float f) {
    unsigned u = __builtin_bit_cast(unsigned, f);
    u += 0x7fffu + ((u >> 16) & 1u);
    return (short)(u >> 16);
}
__device__ inline s16x4 f2bf4(float4 v) {
    s16x4 r; r.x = f2bf(v.x); r.y = f2bf(v.y); r.z = f2bf(v.z); r.w = f2bf(v.w);
    return r;
}
__device__ inline float bf2f(short s) {
    return __builtin_bit_cast(float, ((unsigned)(unsigned short)s) << 16);
}

// ws layout (bytes):
//   cnt     @ 0        : N_NODES int            (0.4 MB)
//   slots   @ 401408   : N_NODES*CAP int        (12.8 MB)
//   emb_bf  @ 13201408 : N_NODES*D bf16         (12.8 MB)
//   acc_bf  @ 26001408 : N_NODES*D bf16         (12.8 MB)
//   ovfc    @ 38801408 : int
//   ovf     @ 38801424 : OVF_CAP int2
//   part    @ 38867200 : N_TILES*64 float       (0.4 MB)
//   part2   @ 39267328 : R1_BLOCKS*64 float     (16 KB)
#define WS_SLOTS_OFF 401408
#define WS_EMBBF_OFF 13201408
#define WS_ACCBF_OFF 26001408
#define WS_OVFC_OFF  38801408
#define WS_OVF_OFF   38801424
#define WS_PART_OFF  38867200
#define WS_PART2_OFF 39267328

// ---------------------------------------------------------------------------
// Region-partitioned CSR fill (R12-proven: 82us). Block r=bIdx&7 scans a
// 2048-edge slice keeping only dst>>14 == r; region's 2MB slot array mostly
// L2-resident. Nontemporal edge reads.
// ---------------------------------------------------------------------------
__global__ __launch_bounds__(256) void fill_kernel(
    const int* __restrict__ edge_src, const int* __restrict__ edge_dst,
    int* __restrict__ cnt, int* __restrict__ slots,
    int* __restrict__ ovf_cnt, int2* __restrict__ ovf) {
    const int r = blockIdx.x & (NR - 1);
    if (r == 7) return;
    const int slice = blockIdx.x >> 3;
    const int base_e = slice * SLICE_EDGES + threadIdx.x * 8;
    if (base_e >= N_EDGES) return;
    const vint4* s4 = (const vint4*)(edge_src + base_e);
    const vint4* d4 = (const vint4*)(edge_dst + base_e);
    vint4 a0 = __builtin_nontemporal_load(s4);
    vint4 a1 = __builtin_nontemporal_load(s4 + 1);
    vint4 b0 = __builtin_nontemporal_load(d4);
    vint4 b1 = __builtin_nontemporal_load(d4 + 1);
    int ss[8] = {a0.x, a0.y, a0.z, a0.w, a1.x, a1.y, a1.z, a1.w};
    int dd[8] = {b0.x, b0.y, b0.z, b0.w, b1.x, b1.y, b1.z, b1.w};
#pragma unroll
    for (int i = 0; i < 8; ++i) {
        if ((dd[i] >> 14) == r) {
            int pos = atomicAdd(&cnt[dd[i]], 1);
            if (pos < CAP) {
                slots[dd[i] * CAP + pos] = ss[i];
            } else {
                int j = atomicAdd(ovf_cnt, 1);
                if (j < OVF_CAP) ovf[j] = make_int2(ss[i], dd[i]);
            }
        }
    }
}

// ---------------------------------------------------------------------------
// emb f32 -> bf16 (R14): halves the gather's random-read bytes (256B->128B
// rows) and acc storage. 1.6M float4 -> s16x4, coalesced; runs concurrently
// with fill (no dependency).
// ---------------------------------------------------------------------------
__global__ __launch_bounds__(256) void cvt_kernel(
    const float* __restrict__ emb, short* __restrict__ emb_bf) {
    const int i = blockIdx.x * 256 + threadIdx.x;  // grid sized exactly
    ((s16x4*)emb_bf)[i] = f2bf4(((const float4*)emb)[i]);
}

// ---------------------------------------------------------------------------
// Atomic-free gather, bf16 (R5-proven structure). One wave per node;
// q=lane>>4 picks slot e+q, c4=lane&15 picks s16x4 column group (8B x 16
// lanes = one 128B row). f32 accumulate; butterfly over q; q==0 stores the
// bf16 acc row. Overflow (normally 0 entries) folded in before the store.
// ---------------------------------------------------------------------------
__global__ __launch_bounds__(256) void gather_kernel(
    const short* __restrict__ emb_bf, const int* __restrict__ cnt,
    const int* __restrict__ slots, short* __restrict__ acc_bf,
    const int* __restrict__ ovf_cnt, const int2* __restrict__ ovf) {
    const int lane = threadIdx.x & 63;
    const int wave = threadIdx.x >> 6;
    const int v = blockIdx.x * 4 + wave;   // grid = N_NODES/4 exactly
    const int q  = lane >> 4;
    const int c4 = lane & 15;
    int deg = cnt[v];
    if (deg > CAP) deg = CAP;
    const int si = slots[(size_t)v * CAP + (lane & (CAP - 1))];
    const s16x4* emb4 = (const s16x4*)emb_bf;  // row = 16 x s16x4

    float sx = 0.f, sy = 0.f, sz = 0.f, sw = 0.f;
    for (int e = 0; e < deg; e += 4) {
        const int idx = e + q;
        const int s = __shfl(si, idx & (CAP - 1));
        if (idx < deg) {
            s16x4 a = emb4[(size_t)s * 16 + c4];
            sx += bf2f(a.x); sy += bf2f(a.y); sz += bf2f(a.z); sw += bf2f(a.w);
        }
    }
#pragma unroll
    for (int off = 16; off < 64; off <<= 1) {
        sx += __shfl_xor(sx, off);
        sy += __shfl_xor(sy, off);
        sz += __shfl_xor(sz, off);
        sw += __shfl_xor(sw, off);
    }
    if (q == 0) {
        int n_ovf = *ovf_cnt;
        if (n_ovf > OVF_CAP) n_ovf = OVF_CAP;
        for (int i = 0; i < n_ovf; ++i) {      // normally zero iterations
            int2 eo = ovf[i];
            if (eo.y == v) {
                s16x4 a = emb4[(size_t)eo.x * 16 + c4];
                sx += bf2f(a.x); sy += bf2f(a.y); sz += bf2f(a.z); sw += bf2f(a.w);
            }
        }
        ((s16x4*)acc_bf)[(size_t)v * 16 + c4] =
            f2bf4(make_float4(sx, sy, sz, sw));
    }
}

// ---------------------------------------------------------------------------
// MFMA final (R12-proven: 253us total). z = [feat|nbr] @ [W1|W2]^T, K=128,
// mfma_f32_16x16x32_bf16 x4 k-steps; W frags hoisted to VGPRs; nbr half of
// A_s now copied straight from bf16 acc (no cvt, half the bytes).
// ---------------------------------------------------------------------------
__global__ __launch_bounds__(256) void final_kernel(
    const float* __restrict__ feat, const short* __restrict__ acc_bf,
    const float* __restrict__ W1, const float* __restrict__ b1,
    const float* __restrict__ W2, const float* __restrict__ b2,
    float* __restrict__ partials) {
    __shared__ short A_s[64 * ASTRIDE];  // [node][feat(0..63)|nbr(64..127)] bf16
    __shared__ short W_s[64 * ASTRIDE];  // [o][W1(0..63)|W2(64..127)] bf16
    __shared__ float red[4][64];

    const int tid  = threadIdx.x;
    const int lane = tid & 63;
    const int wave = tid >> 6;
    const int quad = lane >> 4;
    const int col  = lane & 15;
    const int node0 = blockIdx.x * 64;

    float bias[4];
#pragma unroll
    for (int nb = 0; nb < 4; ++nb) bias[nb] = b1[nb * 16 + col] + b2[nb * 16 + col];

    // Stage W (bf16): 1024 float4 per matrix, 4 per thread, coalesced.
    {
        const float4* W1v = (const float4*)W1;
        const float4* W2v = (const float4*)W2;
#pragma unroll
        for (int i = 0; i < 4; ++i) {
            const int flat = tid + i * 256;
            const int row = flat >> 4, c4 = flat & 15;
            *(s16x4*)&W_s[row * ASTRIDE + c4 * 4]      = f2bf4(W1v[flat]);
            *(s16x4*)&W_s[row * ASTRIDE + 64 + c4 * 4] = f2bf4(W2v[flat]);
        }
    }

    // Stage A: feat (cvt f32->bf16) + acc_bf (straight copy).
    {
        const float4* fv = (const float4*)feat;
        const s16x4* av = (const s16x4*)acc_bf;
#pragma unroll
        for (int i = 0; i < 4; ++i) {
            const int flat = tid + i * 256;
            const int row = flat >> 4, c4 = flat & 15;
            const int node = node0 + row;
            float4 f = make_float4(0.f, 0.f, 0.f, 0.f);
            s16x4 n = (s16x4){0, 0, 0, 0};
            if (node < N_NODES) {
                f = fv[(size_t)node * 16 + c4];
                n = av[(size_t)node * 16 + c4];
            }
            *(s16x4*)&A_s[row * ASTRIDE + c4 * 4]      = f2bf4(f);
            *(s16x4*)&A_s[row * ASTRIDE + 64 + c4 * 4] = n;
        }
    }
    __syncthreads();

    // B-fragments (4 output-blocks x 4 k-steps) hoisted into VGPRs.
    bf16x8 Bf[4][4];
#pragma unroll
    for (int nb = 0; nb < 4; ++nb)
#pragma unroll
        for (int ks = 0; ks < 4; ++ks)
            Bf[nb][ks] = __builtin_bit_cast(bf16x8,
                *(const s16x8*)&W_s[(nb * 16 + col) * ASTRIDE + ks * 32 + quad * 8]);

    f32x4 C[4];
#pragma unroll
    for (int nb = 0; nb < 4; ++nb) C[nb] = (f32x4){0.f, 0.f, 0.f, 0.f};
#pragma unroll
    for (int ks = 0; ks < 4; ++ks) {
        const bf16x8 Af = __builtin_bit_cast(bf16x8,
            *(const s16x8*)&A_s[(wave * 16 + col) * ASTRIDE + ks * 32 + quad * 8]);
#pragma unroll
        for (int nb = 0; nb < 4; ++nb)
            C[nb] = __builtin_amdgcn_mfma_f32_16x16x32_bf16(Af, Bf[nb][ks],
                                                            C[nb], 0, 0, 0);
    }

    // Epilogue: bias + ReLU (C-layout: col=lane&15, row=quad*4+reg), mask OOB
    // nodes, column sums via shfl over quads, cross-wave combine in LDS.
    float sums[4] = {0.f, 0.f, 0.f, 0.f};
#pragma unroll
    for (int nb = 0; nb < 4; ++nb) {
#pragma unroll
        for (int reg = 0; reg < 4; ++reg) {
            const int node = node0 + wave * 16 + quad * 4 + reg;
            float u = C[nb][reg] + bias[nb];
            u = (u > 0.f) ? u : 0.f;
            if (node < N_NODES) sums[nb] += u;
        }
        sums[nb] += __shfl_xor(sums[nb], 16);
        sums[nb] += __shfl_xor(sums[nb], 32);
        if (lane < 16) red[wave][nb * 16 + lane] = sums[nb];
    }
    __syncthreads();
    if (tid < 64) {
        partials[blockIdx.x * 64 + tid] =
            red[0][tid] + red[1][tid] + red[2][tid] + red[3][tid];
    }
}

// ---------------------------------------------------------------------------
// Two-stage partials reduction (R9-proven).
// ---------------------------------------------------------------------------
__global__ __launch_bounds__(256) void reduce1_kernel(
    const float* __restrict__ partials, float* __restrict__ part2) {
    __shared__ float red[4][64];
    const int col = threadIdx.x & 63;
    const int seg = threadIdx.x >> 6;
    const int r0 = blockIdx.x * R1_ROWS;
    int r1 = r0 + R1_ROWS;
    if (r1 > N_TILES) r1 = N_TILES;
    float s = 0.f;
    for (int r = r0 + seg; r < r1; r += 4) s += partials[r * 64 + col];
    red[seg][col] = s;
    __syncthreads();
    if (seg == 0) {
        part2[blockIdx.x * 64 + col] =
            red[0][col] + red[1][col] + red[2][col] + red[3][col];
    }
}

__global__ __launch_bounds__(256) void reduce2_kernel(
    const float* __restrict__ part2, float* __restrict__ out) {
    __shared__ float red[4][64];
    const int col = threadIdx.x & 63;
    const int seg = threadIdx.x >> 6;
    float s = 0.f;
    for (int r = seg; r < R1_BLOCKS; r += 4) s += part2[r * 64 + col];
    red[seg][col] = s;
    __syncthreads();
    if (seg == 0) {
        out[col] = red[0][col] + red[1][col] + red[2][col] + red[3][col];
    }
}

extern "C" void kernel_launch(void* const* d_in, const int* in_sizes, int n_in,
                              void* d_out, int out_size, void* d_ws, size_t ws_size,
                              hipStream_t stream) {
    const float* feat = (const float*)d_in[0];
    const float* emb  = (const float*)d_in[1];
    const float* W1   = (const float*)d_in[2];
    const float* b1   = (const float*)d_in[3];
    const float* W2   = (const float*)d_in[4];
    const float* b2   = (const float*)d_in[5];
    const int* edge_src = (const int*)d_in[6];
    const int* edge_dst = (const int*)d_in[7];
    float* out = (float*)d_out;
    char* ws = (char*)d_ws;

    int*   cnt      = (int*)ws;
    int*   slots    = (int*)(ws + WS_SLOTS_OFF);
    short* emb_bf   = (short*)(ws + WS_EMBBF_OFF);
    short* acc_bf   = (short*)(ws + WS_ACCBF_OFF);
    int*   ovf_cnt  = (int*)(ws + WS_OVFC_OFF);
    int2*  ovf      = (int2*)(ws + WS_OVF_OFF);
    float* partials = (float*)(ws + WS_PART_OFF);
    float* part2    = (float*)(ws + WS_PART2_OFF);

    (void)hipMemsetAsync(cnt, 0, N_NODES * sizeof(int), stream);
    (void)hipMemsetAsync(ovf_cnt, 0, sizeof(int), stream);

    cvt_kernel<<<(N_NODES * D / 4) / 256, 256, 0, stream>>>(emb, emb_bf);
    fill_kernel<<<NR * N_SLICES, 256, 0, stream>>>(edge_src, edge_dst,
                                                   cnt, slots, ovf_cnt, ovf);
    gather_kernel<<<N_NODES / 4, 256, 0, stream>>>(emb_bf, cnt, slots, acc_bf,
                                                   ovf_cnt, ovf);
    final_kernel<<<N_TILES, 256, 0, stream>>>(feat, acc_bf, W1, b1, W2, b2,
                                              partials);
    reduce1_kernel<<<R1_BLOCKS, 256, 0, stream>>>(partials, part2);
    reduce2_kernel<<<1, 256, 0, stream>>>(part2, out);
}

// Round 15
// 269.204 us; speedup vs baseline: 1.2103x; 1.0036x over previous
//
#include <hip/hip_runtime.h>

#define N_NODES 100000
#define N_EDGES 1600000
#define D 64
#define CAP 32         // slot cap per node; Poisson(16): P(deg>32)~1e-5/node
#define OVF_CAP 2048   // overflow edge list (backstop; expected ~0 entries)
#define N_TILES 1563   // (N_NODES + 63) / 64
#define NR 8           // region groups (dst>>14 -> 0..6; r==7 blocks idle)
#define SLICE_EDGES 2048
#define N_SLICES 782   // ceil(N_EDGES / SLICE_EDGES)
#define FILL_BLOCKS (NR * N_SLICES)   // 6256
#define CVT_BLOCKS 12500              // 6250 emb + 6250 feat chunks
#define PREP_GRID 18768               // 3 * 6256; cvt ordinals guarded < 12500
#define R1_BLOCKS 64
#define R1_ROWS 25
#define ASTRIDE 136    // LDS row stride in bf16 elems (128 + 8 pad, 16B-aligned)

typedef int    vint4  __attribute__((ext_vector_type(4)));
typedef short  s16x4  __attribute__((ext_vector_type(4)));
typedef short  s16x8  __attribute__((ext_vector_type(8)));
typedef float  f32x4  __attribute__((ext_vector_type(4)));
typedef __bf16 bf16x8 __attribute__((ext_vector_type(8)));

__device__ inline short f2bf(float f) {
    unsigned u = __builtin_bit_cast(unsigned, f);
    u += 0x7fffu + ((u >> 16) & 1u);
    return (short)(u >> 16);
}
__device__ inline s16x4 f2bf4(float4 v) {
    s16x4 r; r.x = f2bf(v.x); r.y = f2bf(v.y); r.z = f2bf(v.z); r.w = f2bf(v.w);
    return r;
}
__device__ inline float bf2f(short s) {
    return __builtin_bit_cast(float, ((unsigned)(unsigned short)s) << 16);
}

// ws layout (bytes), 128B-aligned, total ~52.03 MB (< R4-proven ws_size):
#define WS_SLOTS_OFF  400128     // cnt @0: 400,000B
#define WS_EMBBF_OFF  13200128   // slots: 12,800,000B
#define WS_FEATBF_OFF 26000128   // emb_bf: 12,800,000B
#define WS_ACCBF_OFF  38800128   // feat_bf: 12,800,000B
#define WS_OVFC_OFF   51600128   // acc_bf: 12,800,000B
#define WS_OVF_OFF    51600256
#define WS_PART_OFF   51616640   // ovf: 2048*8B
#define WS_PART2_OFF  52016768   // part: 400,128B

// ---------------------------------------------------------------------------
// prep: interleaved region-partitioned fill (R12-proven, 82us) + bf16 cvt of
// emb AND feat. Fill is latency-bound (VALU 3%, 1.46 TB/s) so the streaming
// cvt rides its idle capacity instead of costing ~15-20us serial (R14's
// regression). blockIdx%3==0 -> fill ordinal i=b/3: region r=b&7 keeps all
// writers of region r on one XCD (3 invertible mod 8; each (slice,region)
// covered once: slice = i>>3). Other blocks -> cvt chunk j (guarded <12500).
// ---------------------------------------------------------------------------
__global__ __launch_bounds__(256) void prep_kernel(
    const int* __restrict__ edge_src, const int* __restrict__ edge_dst,
    const float* __restrict__ emb, const float* __restrict__ feat,
    int* __restrict__ cnt, int* __restrict__ slots,
    short* __restrict__ emb_bf, short* __restrict__ feat_bf,
    int* __restrict__ ovf_cnt, int2* __restrict__ ovf) {
    const int b = blockIdx.x;
    const int tid = threadIdx.x;
    if (b % 3 == 0) {
        // ---- fill ----
        const int r = b & (NR - 1);
        if (r == 7) return;                    // region 7 empty (dst < 114688)
        const int i = b / 3;                   // fill ordinal 0..6255
        const int slice = i >> 3;
        const int base_e = slice * SLICE_EDGES + tid * 8;
        if (base_e >= N_EDGES) return;         // ragged last slice
        const vint4* s4 = (const vint4*)(edge_src + base_e);
        const vint4* d4 = (const vint4*)(edge_dst + base_e);
        vint4 a0 = __builtin_nontemporal_load(s4);
        vint4 a1 = __builtin_nontemporal_load(s4 + 1);
        vint4 b0 = __builtin_nontemporal_load(d4);
        vint4 b1 = __builtin_nontemporal_load(d4 + 1);
        int ss[8] = {a0.x, a0.y, a0.z, a0.w, a1.x, a1.y, a1.z, a1.w};
        int dd[8] = {b0.x, b0.y, b0.z, b0.w, b1.x, b1.y, b1.z, b1.w};
#pragma unroll
        for (int k = 0; k < 8; ++k) {
            if ((dd[k] >> 14) == r) {
                int pos = atomicAdd(&cnt[dd[k]], 1);
                if (pos < CAP) {
                    slots[dd[k] * CAP + pos] = ss[k];
                } else {
                    int j = atomicAdd(ovf_cnt, 1);
                    if (j < OVF_CAP) ovf[j] = make_int2(ss[k], dd[k]);
                }
            }
        }
    } else {
        // ---- cvt: j = cvt ordinal ----
        const int q3 = b / 3;
        const int j = (b % 3 == 1) ? 2 * q3 : 2 * q3 + 1;
        if (j >= CVT_BLOCKS) return;
        if (j < 6250) {
            const int g = j * 256 + tid;       // float4 index into emb
            ((s16x4*)emb_bf)[g] = f2bf4(((const float4*)emb)[g]);
        } else {
            const int g = (j - 6250) * 256 + tid;
            ((s16x4*)feat_bf)[g] = f2bf4(((const float4*)feat)[g]);
        }
    }
}

// ---------------------------------------------------------------------------
// Atomic-free gather, bf16, TWO nodes per wave (R15). R14 showed halved
// bytes didn't help -> latency-bound, so double the independent load chains:
// one 256B slot read covers both adjacent rows (lanes 0-31 = v0, 32-63 = v1);
// each round issues two independent row-load instructions. Grid = N_NODES/8.
// ---------------------------------------------------------------------------
__global__ __launch_bounds__(256) void gather_kernel(
    const short* __restrict__ emb_bf, const int* __restrict__ cnt,
    const int* __restrict__ slots, short* __restrict__ acc_bf,
    const int* __restrict__ ovf_cnt, const int2* __restrict__ ovf) {
    const int lane = threadIdx.x & 63;
    const int wave = threadIdx.x >> 6;
    const int quad = lane >> 4;
    const int c4   = lane & 15;
    const int v0 = blockIdx.x * 8 + wave * 2;   // grid covers exactly
    const int v1 = v0 + 1;
    int deg0 = cnt[v0]; if (deg0 > CAP) deg0 = CAP;
    int deg1 = cnt[v1]; if (deg1 > CAP) deg1 = CAP;
    const int si = slots[(size_t)v0 * CAP + lane];  // 256B: both nodes' rows
    const s16x4* emb4 = (const s16x4*)emb_bf;

    float s0x = 0.f, s0y = 0.f, s0z = 0.f, s0w = 0.f;
    float s1x = 0.f, s1y = 0.f, s1z = 0.f, s1w = 0.f;
    const int maxd = (deg0 > deg1) ? deg0 : deg1;
    for (int e = 0; e < maxd; e += 4) {
        const int idx = e + quad;
        const int r0 = __shfl(si, idx & 31);
        const int r1 = __shfl(si, 32 + (idx & 31));
        if (idx < deg0) {
            s16x4 a = emb4[(size_t)r0 * 16 + c4];
            s0x += bf2f(a.x); s0y += bf2f(a.y); s0z += bf2f(a.z); s0w += bf2f(a.w);
        }
        if (idx < deg1) {
            s16x4 a = emb4[(size_t)r1 * 16 + c4];
            s1x += bf2f(a.x); s1y += bf2f(a.y); s1z += bf2f(a.z); s1w += bf2f(a.w);
        }
    }
#pragma unroll
    for (int off = 16; off < 64; off <<= 1) {
        s0x += __shfl_xor(s0x, off); s0y += __shfl_xor(s0y, off);
        s0z += __shfl_xor(s0z, off); s0w += __shfl_xor(s0w, off);
        s1x += __shfl_xor(s1x, off); s1y += __shfl_xor(s1y, off);
        s1z += __shfl_xor(s1z, off); s1w += __shfl_xor(s1w, off);
    }
    int n_ovf = *ovf_cnt;
    if (n_ovf > OVF_CAP) n_ovf = OVF_CAP;
    if (quad == 0) {
        for (int i = 0; i < n_ovf; ++i) {      // normally zero iterations
            int2 eo = ovf[i];
            if (eo.y == v0) {
                s16x4 a = emb4[(size_t)eo.x * 16 + c4];
                s0x += bf2f(a.x); s0y += bf2f(a.y); s0z += bf2f(a.z); s0w += bf2f(a.w);
            }
        }
        ((s16x4*)acc_bf)[(size_t)v0 * 16 + c4] =
            f2bf4(make_float4(s0x, s0y, s0z, s0w));
    } else if (quad == 1) {
        for (int i = 0; i < n_ovf; ++i) {
            int2 eo = ovf[i];
            if (eo.y == v1) {
                s16x4 a = emb4[(size_t)eo.x * 16 + c4];
                s1x += bf2f(a.x); s1y += bf2f(a.y); s1z += bf2f(a.z); s1w += bf2f(a.w);
            }
        }
        ((s16x4*)acc_bf)[(size_t)v1 * 16 + c4] =
            f2bf4(make_float4(s1x, s1y, s1z, s1w));
    }
}

// ---------------------------------------------------------------------------
// MFMA final (R12-proven). z = [feat|nbr] @ [W1|W2]^T, K=128,
// mfma_f32_16x16x32_bf16 x4; W frags hoisted to VGPRs. A-stage is now two
// straight bf16 copies (feat_bf + acc_bf): FETCH 39 -> 26 MB, no cvt VALU.
// ---------------------------------------------------------------------------
__global__ __launch_bounds__(256) void final_kernel(
    const short* __restrict__ feat_bf, const short* __restrict__ acc_bf,
    const float* __restrict__ W1, const float* __restrict__ b1,
    const float* __restrict__ W2, const float* __restrict__ b2,
    float* __restrict__ partials) {
    __shared__ short A_s[64 * ASTRIDE];  // [node][feat(0..63)|nbr(64..127)] bf16
    __shared__ short W_s[64 * ASTRIDE];  // [o][W1(0..63)|W2(64..127)] bf16
    __shared__ float red[4][64];

    const int tid  = threadIdx.x;
    const int lane = tid & 63;
    const int wave = tid >> 6;
    const int quad = lane >> 4;
    const int col  = lane & 15;
    const int node0 = blockIdx.x * 64;

    float bias[4];
#pragma unroll
    for (int nb = 0; nb < 4; ++nb) bias[nb] = b1[nb * 16 + col] + b2[nb * 16 + col];

    {
        const float4* W1v = (const float4*)W1;
        const float4* W2v = (const float4*)W2;
#pragma unroll
        for (int i = 0; i < 4; ++i) {
            const int flat = tid + i * 256;
            const int row = flat >> 4, cc = flat & 15;
            *(s16x4*)&W_s[row * ASTRIDE + cc * 4]      = f2bf4(W1v[flat]);
            *(s16x4*)&W_s[row * ASTRIDE + 64 + cc * 4] = f2bf4(W2v[flat]);
        }
    }
    {
        const s16x4* fv = (const s16x4*)feat_bf;
        const s16x4* av = (const s16x4*)acc_bf;
#pragma unroll
        for (int i = 0; i < 4; ++i) {
            const int flat = tid + i * 256;
            const int row = flat >> 4, cc = flat & 15;
            const int node = node0 + row;
            s16x4 f = (s16x4){0, 0, 0, 0};
            s16x4 n = (s16x4){0, 0, 0, 0};
            if (node < N_NODES) {
                f = fv[(size_t)node * 16 + cc];
                n = av[(size_t)node * 16 + cc];
            }
            *(s16x4*)&A_s[row * ASTRIDE + cc * 4]      = f;
            *(s16x4*)&A_s[row * ASTRIDE + 64 + cc * 4] = n;
        }
    }
    __syncthreads();

    bf16x8 Bf[4][4];
#pragma unroll
    for (int nb = 0; nb < 4; ++nb)
#pragma unroll
        for (int ks = 0; ks < 4; ++ks)
            Bf[nb][ks] = __builtin_bit_cast(bf16x8,
                *(const s16x8*)&W_s[(nb * 16 + col) * ASTRIDE + ks * 32 + quad * 8]);

    f32x4 C[4];
#pragma unroll
    for (int nb = 0; nb < 4; ++nb) C[nb] = (f32x4){0.f, 0.f, 0.f, 0.f};
#pragma unroll
    for (int ks = 0; ks < 4; ++ks) {
        const bf16x8 Af = __builtin_bit_cast(bf16x8,
            *(const s16x8*)&A_s[(wave * 16 + col) * ASTRIDE + ks * 32 + quad * 8]);
#pragma unroll
        for (int nb = 0; nb < 4; ++nb)
            C[nb] = __builtin_amdgcn_mfma_f32_16x16x32_bf16(Af, Bf[nb][ks],
                                                            C[nb], 0, 0, 0);
    }

    float sums[4] = {0.f, 0.f, 0.f, 0.f};
#pragma unroll
    for (int nb = 0; nb < 4; ++nb) {
#pragma unroll
        for (int reg = 0; reg < 4; ++reg) {
            const int node = node0 + wave * 16 + quad * 4 + reg;
            float u = C[nb][reg] + bias[nb];
            u = (u > 0.f) ? u : 0.f;
            if (node < N_NODES) sums[nb] += u;
        }
        sums[nb] += __shfl_xor(sums[nb], 16);
        sums[nb] += __shfl_xor(sums[nb], 32);
        if (lane < 16) red[wave][nb * 16 + lane] = sums[nb];
    }
    __syncthreads();
    if (tid < 64) {
        partials[blockIdx.x * 64 + tid] =
            red[0][tid] + red[1][tid] + red[2][tid] + red[3][tid];
    }
}

// ---------------------------------------------------------------------------
// Two-stage partials reduction (R9-proven).
// ---------------------------------------------------------------------------
__global__ __launch_bounds__(256) void reduce1_kernel(
    const float* __restrict__ partials, float* __restrict__ part2) {
    __shared__ float red[4][64];
    const int col = threadIdx.x & 63;
    const int seg = threadIdx.x >> 6;
    const int r0 = blockIdx.x * R1_ROWS;
    int r1 = r0 + R1_ROWS;
    if (r1 > N_TILES) r1 = N_TILES;
    float s = 0.f;
    for (int r = r0 + seg; r < r1; r += 4) s += partials[r * 64 + col];
    red[seg][col] = s;
    __syncthreads();
    if (seg == 0) {
        part2[blockIdx.x * 64 + col] =
            red[0][col] + red[1][col] + red[2][col] + red[3][col];
    }
}

__global__ __launch_bounds__(256) void reduce2_kernel(
    const float* __restrict__ part2, float* __restrict__ out) {
    __shared__ float red[4][64];
    const int col = threadIdx.x & 63;
    const int seg = threadIdx.x >> 6;
    float s = 0.f;
    for (int r = seg; r < R1_BLOCKS; r += 4) s += part2[r * 64 + col];
    red[seg][col] = s;
    __syncthreads();
    if (seg == 0) {
        out[col] = red[0][col] + red[1][col] + red[2][col] + red[3][col];
    }
}

extern "C" void kernel_launch(void* const* d_in, const int* in_sizes, int n_in,
                              void* d_out, int out_size, void* d_ws, size_t ws_size,
                              hipStream_t stream) {
    const float* feat = (const float*)d_in[0];
    const float* emb  = (const float*)d_in[1];
    const float* W1   = (const float*)d_in[2];
    const float* b1   = (const float*)d_in[3];
    const float* W2   = (const float*)d_in[4];
    const float* b2   = (const float*)d_in[5];
    const int* edge_src = (const int*)d_in[6];
    const int* edge_dst = (const int*)d_in[7];
    float* out = (float*)d_out;
    char* ws = (char*)d_ws;

    int*   cnt      = (int*)ws;
    int*   slots    = (int*)(ws + WS_SLOTS_OFF);
    short* emb_bf   = (short*)(ws + WS_EMBBF_OFF);
    short* feat_bf  = (short*)(ws + WS_FEATBF_OFF);
    short* acc_bf   = (short*)(ws + WS_ACCBF_OFF);
    int*   ovf_cnt  = (int*)(ws + WS_OVFC_OFF);
    int2*  ovf      = (int2*)(ws + WS_OVF_OFF);
    float* partials = (float*)(ws + WS_PART_OFF);
    float* part2    = (float*)(ws + WS_PART2_OFF);

    (void)hipMemsetAsync(cnt, 0, N_NODES * sizeof(int), stream);
    (void)hipMemsetAsync(ovf_cnt, 0, sizeof(int), stream);

    prep_kernel<<<PREP_GRID, 256, 0, stream>>>(edge_src, edge_dst, emb, feat,
                                               cnt, slots, emb_bf, feat_bf,
                                               ovf_cnt, ovf);
    gather_kernel<<<N_NODES / 8, 256, 0, stream>>>(emb_bf, cnt, slots, acc_bf,
                                                   ovf_cnt, ovf);
    final_kernel<<<N_TILES, 256, 0, stream>>>(feat_bf, acc_bf, W1, b1, W2, b2,
                                              partials);
    reduce1_kernel<<<R1_BLOCKS, 256, 0, stream>>>(partials, part2);
    reduce2_kernel<<<1, 256, 0, stream>>>(part2, out);
}